// Round 5
// baseline (51.549 us; speedup 1.0000x reference)
//
#include <hip/hip_runtime.h>

#define B_  2048
#define I_  256
#define H_  512
#define D_  768
#define K_  32

typedef unsigned short ushort_t;
typedef unsigned int uint_t;
typedef __attribute__((ext_vector_type(8))) __bf16 bf16x8;
typedef __attribute__((ext_vector_type(4))) float f32x4;

__device__ __forceinline__ ushort_t f2bf(float f) {
  uint_t u = __float_as_uint(f);
  u += 0x7fffu + ((u >> 16) & 1u);   // RNE
  return (ushort_t)(u >> 16);
}
__device__ __forceinline__ float fast_sigmoid(float x) {
  return 1.f / (1.f + __expf(-x));
}
__device__ __forceinline__ float fast_tanh(float x) {
  float t = __expf(2.f * fabsf(x));          // overflow -> inf -> r = 1
  float r = 1.f - 2.f / (t + 1.f);
  return copysignf(r, x);
}
__device__ __forceinline__ void gload16(const void* g, void* l) {
  __builtin_amdgcn_global_load_lds(
      (const __attribute__((address_space(1))) void*)g,
      (__attribute__((address_space(3))) void*)l, 16, 0, 0);
}

// ---- prep kernel: blocks 0..1535 transpose Wc -> wcT bf16;
//      blocks 1536..2303 run the per-feature KAN MLP (phase 1) with direct
//      (untransposed) weight loads, writing uT[g][b][d] bf16 ----
__global__ __launch_bounds__(256) void kan_prep(
    const float* __restrict__ x, const float* __restrict__ hp,
    const float* __restrict__ W1, const float* __restrict__ b1,
    const float* __restrict__ W2, const float* __restrict__ b2,
    const float* __restrict__ Wc,
    ushort_t* __restrict__ wcT, ushort_t* __restrict__ uT) {
  __shared__ float ttile[32][33];
  int bid = blockIdx.x;
  if (bid < 1536) {
    int tx = threadIdx.x & 31, ty = threadIdx.x >> 5;
    int g = bid / 384;
    int rem = bid % 384;
    int d0 = (rem / 16) * 32;
    int h0 = (rem % 16) * 32;
#pragma unroll
    for (int i = 0; i < 4; ++i) {
      int r = ty + i * 8;
      ttile[r][tx] = Wc[((size_t)g * D_ + d0 + r) * H_ + h0 + tx];
    }
    __syncthreads();
#pragma unroll
    for (int i = 0; i < 4; ++i) {
      int r = ty + i * 8;                     // h index
      wcT[((size_t)g * H_ + h0 + r) * D_ + d0 + tx] = f2bf(ttile[tx][r]);
    }
  } else {
    int p = bid - 1536;
    int combo = p >> 6;                // 0..11
    int bc = p & 63;
    int g = combo & 3;
    int dc = combo >> 2;               // 0: x[:,0:256], 1: hp[:,0:256], 2: hp[:,256:512]
    int t = threadIdx.x;
    int d = dc * 256 + t;

    // per-lane contiguous 128B weight rows (L2-resident across bc-blocks)
    f32x4 w1v[8], bbv[8], w2v[8];
    const float* W1p = W1 + ((size_t)g * D_ + d) * K_;
    const float* b1p = b1 + ((size_t)g * D_ + d) * K_;
    const float* W2p = W2 + ((size_t)g * D_ + d) * K_;
#pragma unroll
    for (int q = 0; q < 8; ++q) {
      w1v[q] = *(const f32x4*)(W1p + q * 4);
      bbv[q] = *(const f32x4*)(b1p + q * 4);
      w2v[q] = *(const f32x4*)(W2p + q * 4);
    }
    float bias = b2[(size_t)g * D_ + d];

    const float* src = (dc == 0) ? (x + t) : (hp + ((dc == 1) ? t : t + 256));
    int stride = (dc == 0) ? I_ : H_;
    int b0 = bc * 32;

#pragma unroll
    for (int bb8 = 0; bb8 < 32; bb8 += 8) {
      float cv[8], acc[8];
#pragma unroll
      for (int j = 0; j < 8; ++j) {
        cv[j] = src[(size_t)(b0 + bb8 + j) * stride];
        acc[j] = bias;
      }
#pragma unroll
      for (int q = 0; q < 8; ++q)
#pragma unroll
        for (int e = 0; e < 4; ++e) {
          float w1 = w1v[q][e], bbk = bbv[q][e], w2 = w2v[q][e];
#pragma unroll
          for (int j = 0; j < 8; ++j) {
            float h = fmaxf(fmaf(cv[j], w1, bbk), 0.f);
            acc[j] = fmaf(h, w2, acc[j]);
          }
        }
#pragma unroll
      for (int j = 0; j < 8; ++j)
        uT[((size_t)g * B_ + b0 + bb8 + j) * D_ + d] = f2bf(acc[j]);
    }
  }
}

// ---- phase 2 v5: 32(b) x 64(h) x 4 gates per block, 8 waves,
//      global_load_lds + 3-deep counted-vmcnt pipeline (T3+T4),
//      XCD-aware block swizzle (T1), setprio (T5), fused LSTM epilogue ----
#define TB 32
#define TH 64
#define BK 32
#define NT (D_ / BK)                 // 24
#define BUFSZ 24576                  // A 8KB + B 16KB per buffer
#define NBUF 3

__global__ __launch_bounds__(512, 4) void kan_phase2(
    const ushort_t* __restrict__ uT, const ushort_t* __restrict__ wcT,
    const float* __restrict__ bc, const float* __restrict__ cprev,
    float* __restrict__ out) {
  __shared__ __align__(16) char smem[NBUF * BUFSZ];   // 73728 B
  // XCD-aware swizzle: xcd = flat%8 gets bx in [8*xcd, 8*xcd+8), all by.
  // Per-XCD L2 working set: 8 A-panels (1.5MB) + full wcT (3MB) ~ 4.5MB.
  const int flat = blockIdx.x;
  const int bxx = ((flat & 7) << 3) | ((flat >> 3) & 7);
  const int byy = flat >> 6;
  const int b0 = bxx * TB;
  const int h0 = byy * TH;
  const int t = threadIdx.x;
  const int w = t >> 6;
  const int l = t & 63;

  // ---- staging source addresses (pre-swizzled global chunks, linear LDS dest) ----
  const int ag   = w >> 1;
  const int arow = (w & 1) * 16 + (l >> 2);
  const int acg  = (l & 3) ^ ((arow ^ (arow >> 2)) & 3);
  const ushort_t* asrc = uT + ((size_t)ag * B_ + b0 + arow) * D_ + acg * 8;
  const int bg0  = w >> 2;
  const int brow = (w & 3) * 16 + (l >> 2);
  const int bcg  = (l & 3) ^ ((brow ^ (brow >> 2)) & 3);
  const ushort_t* bsrc0 = wcT + ((size_t)bg0 * H_ + h0 + brow) * D_ + bcg * 8;
  const ushort_t* bsrc1 = bsrc0 + (size_t)2 * H_ * D_;
  const int aoffL  = (w << 10) + (l << 4);            // LDS offsets within a buffer
  const int boff0L = 8192 + (w << 10) + (l << 4);
  const int boff1L = 8192 + ((w + 8) << 10) + (l << 4);

  // ---- compute-side LDS byte offsets (read swizzle = same involution) ----
  const int gate = w >> 1, nh = w & 1;
  const int frow = l & 15, c0 = l >> 4;
  const int cx = ((c0 ^ ((frow ^ (frow >> 2)) & 3)) << 4);
  int aoff[2], boff[2];
#pragma unroll
  for (int m = 0; m < 2; ++m)
    aoff[m] = ((gate * 32 + m * 16 + frow) << 6) + cx;
#pragma unroll
  for (int n = 0; n < 2; ++n)
    boff[n] = 8192 + ((gate * 64 + nh * 32 + n * 16 + frow) << 6) + cx;

  // ---- accumulators, bias folded in (C col = lane&15) ----
  f32x4 acc[2][2];
#pragma unroll
  for (int n = 0; n < 2; ++n) {
    float bv = bc[(size_t)gate * H_ + h0 + nh * 32 + n * 16 + frow];
#pragma unroll
    for (int m = 0; m < 2; ++m) acc[m][n] = (f32x4){bv, bv, bv, bv};
  }

  auto stage = [&](int bufoff, int dke) {
    gload16(asrc + dke, smem + bufoff + aoffL);
    gload16(bsrc0 + dke, smem + bufoff + boff0L);
    gload16(bsrc1 + dke, smem + bufoff + boff1L);
  };
  auto compute = [&](const char* bb) {
    bf16x8 af0 = *(const bf16x8*)(bb + aoff[0]);
    bf16x8 af1 = *(const bf16x8*)(bb + aoff[1]);
    bf16x8 bf0 = *(const bf16x8*)(bb + boff[0]);
    bf16x8 bf1 = *(const bf16x8*)(bb + boff[1]);
    __builtin_amdgcn_s_setprio(1);
    acc[0][0] = __builtin_amdgcn_mfma_f32_16x16x32_bf16(af0, bf0, acc[0][0], 0, 0, 0);
    acc[0][1] = __builtin_amdgcn_mfma_f32_16x16x32_bf16(af0, bf1, acc[0][1], 0, 0, 0);
    acc[1][0] = __builtin_amdgcn_mfma_f32_16x16x32_bf16(af1, bf0, acc[1][0], 0, 0, 0);
    acc[1][1] = __builtin_amdgcn_mfma_f32_16x16x32_bf16(af1, bf1, acc[1][1], 0, 0, 0);
    __builtin_amdgcn_s_setprio(0);
  };

  // ---- prologue: 2 tiles in flight ----
  stage(0, 0);
  stage(BUFSZ, BK);
  int roff = 0, soff = 2 * BUFSZ;
  for (int s = 0; s < NT - 1; ++s) {
    // wait own stage(s) complete (3 newest = stage(s+1) stay in flight), then sync
    asm volatile("s_waitcnt vmcnt(3)" ::: "memory");
    __builtin_amdgcn_s_barrier();
    if (s + 2 < NT) {
      stage(soff, (s + 2) * BK);
      soff += BUFSZ; if (soff == NBUF * BUFSZ) soff = 0;
    }
    compute(smem + roff);
    roff += BUFSZ; if (roff == NBUF * BUFSZ) roff = 0;
  }
  asm volatile("s_waitcnt vmcnt(0)" ::: "memory");
  __builtin_amdgcn_s_barrier();
  compute(smem + roff);
  __syncthreads();                         // all LDS reads done before gf overlay

  // ---- epilogue: exchange gate tiles via LDS [4][32][68] f32, fused LSTM ----
  float* gf = (float*)smem;
#pragma unroll
  for (int m = 0; m < 2; ++m)
#pragma unroll
    for (int n = 0; n < 2; ++n)
#pragma unroll
      for (int e = 0; e < 4; ++e) {
        int row = m * 16 + (l >> 4) * 4 + e;
        int col = nh * 32 + n * 16 + frow;
        gf[((size_t)gate * 32 + row) * 68 + col] = acc[m][n][e];
      }
  __syncthreads();

  {
    int row = t >> 4;                      // 0..31
    int ch = t & 15;                       // h-chunk of 4
    int b = b0 + row;
    int hc = h0 + ch * 4;
    f32x4 g0 = *(const f32x4*)&gf[((size_t)0 * 32 + row) * 68 + ch * 4];
    f32x4 g1 = *(const f32x4*)&gf[((size_t)1 * 32 + row) * 68 + ch * 4];
    f32x4 g2 = *(const f32x4*)&gf[((size_t)2 * 32 + row) * 68 + ch * 4];
    f32x4 g3 = *(const f32x4*)&gf[((size_t)3 * 32 + row) * 68 + ch * 4];
    f32x4 cp = *(const f32x4*)&cprev[(size_t)b * H_ + hc];
    f32x4 hv, cv;
#pragma unroll
    for (int e = 0; e < 4; ++e) {
      float ft = fast_sigmoid(g0[e]);
      float it = fast_sigmoid(g1[e]);
      float ot = fast_sigmoid(g2[e]);
      float tc = fast_tanh(g3[e]);
      float cn = ft * cp[e] + it * tc;
      cv[e] = cn;
      hv[e] = ot * fast_tanh(cn);
    }
    *(f32x4*)&out[(size_t)b * H_ + hc] = hv;
    *(f32x4*)&out[(size_t)B_ * H_ + (size_t)b * H_ + hc] = cv;
  }
}

extern "C" void kernel_launch(void* const* d_in, const int* in_sizes, int n_in,
                              void* d_out, int out_size, void* d_ws, size_t ws_size,
                              hipStream_t stream) {
  const float* x  = (const float*)d_in[0];
  const float* hp = (const float*)d_in[1];
  const float* cp = (const float*)d_in[2];
  const float* W1 = (const float*)d_in[3];
  const float* b1 = (const float*)d_in[4];
  const float* W2 = (const float*)d_in[5];
  const float* b2 = (const float*)d_in[6];
  const float* Wc = (const float*)d_in[7];
  const float* bc = (const float*)d_in[8];
  float* out = (float*)d_out;

  // workspace layout
  ushort_t* wcT = (ushort_t*)d_ws;                  // 4*512*768 bf16
  ushort_t* uT  = wcT + (size_t)4 * H_ * D_;        // 4*2048*768 bf16

  kan_prep<<<2304, 256, 0, stream>>>(x, hp, W1, b1, W2, b2, Wc, wcT, uT);
  kan_phase2<<<(B_ / TB) * (H_ / TH), 512, 0, stream>>>(uT, wcT, bc, cp, out);
}